// Round 11
// baseline (350.850 us; speedup 1.0000x reference)
//
#include <hip/hip_runtime.h>
#include <hip/hip_bf16.h>

#define NLAYER 4
#define DDIM 256
#define TSEQ 4096
#define NBATCH 8
#define MROWS (NBATCH * TSEQ)   // 32768
#define CLEN 32                 // chunk length for parallel scan
#define NCHUNK (TSEQ / CLEN)    // 128

typedef float f32x4 __attribute__((ext_vector_type(4)));
typedef short bf16x8 __attribute__((ext_vector_type(8)));

__device__ __forceinline__ float bf2f(unsigned short u) {
    union { unsigned int i; float f; } v; v.i = ((unsigned int)u) << 16; return v.f;
}
__device__ __forceinline__ unsigned short f2bf(float f) {
    union { float f; unsigned int i; } v; v.f = f;
    unsigned int r = v.i + 0x7fffu + ((v.i >> 16) & 1u);
    return (unsigned short)(r >> 16);
}

// async global->LDS, 16B per lane; lds base must be wave-uniform (HW adds lane*16)
__device__ __forceinline__ void gload16(const unsigned short* g, unsigned short* l) {
    __builtin_amdgcn_global_load_lds(
        (const __attribute__((address_space(1))) unsigned int*)g,
        (__attribute__((address_space(3))) unsigned int*)l, 16, 0, 0);
}

// ---------------- prepack: weights -> bf16 (gamma folded into B, -C_im), lambda, lambda^CLEN ----
__global__ __launch_bounds__(256) void prepack_kernel(
    const float* __restrict__ nu_log, const float* __restrict__ theta_log,
    const float* __restrict__ gamma_log,
    const float* __restrict__ B_re, const float* __restrict__ B_im,
    const float* __restrict__ C_re, const float* __restrict__ C_im,
    const float* __restrict__ Wg,
    unsigned short* __restrict__ wBre, unsigned short* __restrict__ wBim,
    unsigned short* __restrict__ wWg, unsigned short* __restrict__ wCre,
    unsigned short* __restrict__ wCimn,
    float* __restrict__ lam_re, float* __restrict__ lam_im,
    float* __restrict__ lamC_re, float* __restrict__ lamC_im)
{
    int idx = blockIdx.x * 256 + threadIdx.x;
    const int total = NLAYER * DDIM * DDIM;
    if (idx < total) {
        int l = idx >> 16;
        int e = (idx >> 8) & 255;
        float gam = expf(gamma_log[l * DDIM + e]);
        wBre[idx]  = f2bf(B_re[idx] * gam);
        wBim[idx]  = f2bf(B_im[idx] * gam);
        wWg[idx]   = f2bf(Wg[idx]);
        wCre[idx]  = f2bf(C_re[idx]);
        wCimn[idx] = f2bf(-C_im[idx]);
    }
    if (idx < NLAYER * DDIM) {
        float mag = expf(-expf(nu_log[idx]));
        float th  = expf(theta_log[idx]);
        float ar = mag * cosf(th);
        float ai = mag * sinf(th);
        lam_re[idx] = ar;
        lam_im[idx] = ai;
        #pragma unroll
        for (int s = 0; s < 5; ++s) {   // lambda^32
            float nr = ar * ar - ai * ai;
            float ni = 2.0f * ar * ai;
            ar = nr; ai = ni;
        }
        lamC_re[idx] = ar;
        lamC_im[idx] = ai;
    }
}

// ---------------- LayerNorm (layer 0 only): one wave per row, 4 rows/block ---------------------
__global__ __launch_bounds__(256) void ln_kernel(
    const float* __restrict__ u, unsigned short* __restrict__ z,
    const float* __restrict__ scale, const float* __restrict__ bias,
    float2* __restrict__ rowStats)
{
    int wid = threadIdx.x >> 6;
    int lane = threadIdx.x & 63;
    int row = blockIdx.x * 4 + wid;
    const float4 v = *reinterpret_cast<const float4*>(u + (size_t)row * DDIM + lane * 4);
    float s  = v.x + v.y + v.z + v.w;
    float s2 = v.x * v.x + v.y * v.y + v.z * v.z + v.w * v.w;
    #pragma unroll
    for (int off = 32; off > 0; off >>= 1) {
        s  += __shfl_xor(s, off);
        s2 += __shfl_xor(s2, off);
    }
    float mu  = s * (1.0f / DDIM);
    float var = s2 * (1.0f / DDIM) - mu * mu;
    float inv = rsqrtf(var + 1e-5f);
    if (lane == 0) { float2 st; st.x = mu; st.y = inv; rowStats[row] = st; }
    float zv[4] = { v.x, v.y, v.z, v.w };
    ushort4 o;
    unsigned short* op = (unsigned short*)&o;
    #pragma unroll
    for (int j = 0; j < 4; ++j) {
        int d = lane * 4 + j;
        op[j] = f2bf((zv[j] - mu) * inv * scale[d] + bias[d]);
    }
    *reinterpret_cast<ushort4*>(z + (size_t)row * DDIM + lane * 4) = o;
}

// ---------------- GEMM1 (fused 3-matrix) + chunk-finals epilogue --------------------------------
// grid (256, 4): m0 = bx*128, n0 = by*64. Writes bu INTERLEAVED (im<<16|re) into buri.
__global__ __launch_bounds__(256) void gemm1_kernel(
    const unsigned short* __restrict__ z,
    const unsigned short* __restrict__ wBre, const unsigned short* __restrict__ wBim,
    const unsigned short* __restrict__ wWg,
    unsigned int* __restrict__ buri, unsigned short* __restrict__ sg,
    const float* __restrict__ lam_re, const float* __restrict__ lam_im,
    float2* __restrict__ fin)
{
    const int m0 = blockIdx.x * 128;
    const int n0 = blockIdx.y * 64;

    __shared__ unsigned short Al[128 * 64];      // 16 KB
    __shared__ unsigned short Wl[3][64 * 64];    // 24 KB

    const int tid = threadIdx.x;
    const int lane = tid & 63;
    const int wid = tid >> 6;
    const int wr = wid >> 1, wc = wid & 1;
    const int lr = lane >> 3;      // row within 8-row segment
    const int lc = lane & 7;       // 16B chunk within row

    f32x4 acc[3][4][2] = {};

    for (int ko = 0; ko < 256; ko += 64) {
        #pragma unroll
        for (int it = 0; it < 4; ++it) {
            int s = wid * 4 + it;
            int r = s * 8 + lr;
            int gc = lc ^ (r & 7);
            gload16(z + (size_t)(m0 + r) * 256 + ko + gc * 8, &Al[s * 512]);
        }
        #pragma unroll
        for (int it = 0; it < 2; ++it) {
            int s = wid * 2 + it;
            int r = s * 8 + lr;
            int gc = lc ^ (r & 7);
            size_t off = (size_t)(n0 + r) * 256 + ko + gc * 8;
            gload16(wBre + off, &Wl[0][s * 512]);
            gload16(wBim + off, &Wl[1][s * 512]);
            gload16(wWg  + off, &Wl[2][s * 512]);
        }
        __syncthreads();

        #pragma unroll
        for (int k2 = 0; k2 < 64; k2 += 32) {
            int ac = (k2 >> 3) + (lane >> 4);
            bf16x8 a[4];
            #pragma unroll
            for (int mi = 0; mi < 4; ++mi) {
                int ar = wr * 64 + mi * 16 + (lane & 15);
                a[mi] = *reinterpret_cast<const bf16x8*>(&Al[ar * 64 + ((ac ^ (ar & 7)) * 8)]);
            }
            int br0 = wc * 32 + (lane & 15);
            int br1 = br0 + 16;
            #pragma unroll
            for (int mat = 0; mat < 3; ++mat) {
                bf16x8 b0 = *reinterpret_cast<const bf16x8*>(&Wl[mat][br0 * 64 + ((ac ^ (br0 & 7)) * 8)]);
                bf16x8 b1 = *reinterpret_cast<const bf16x8*>(&Wl[mat][br1 * 64 + ((ac ^ (br1 & 7)) * 8)]);
                #pragma unroll
                for (int mi = 0; mi < 4; ++mi) {
                    acc[mat][mi][0] = __builtin_amdgcn_mfma_f32_16x16x32_bf16(a[mi], b0, acc[mat][mi][0], 0, 0, 0);
                    acc[mat][mi][1] = __builtin_amdgcn_mfma_f32_16x16x32_bf16(a[mi], b1, acc[mat][mi][1], 0, 0, 0);
                }
            }
        }
        __syncthreads();
    }

    // global writes (buri packed, sg) + LDS transpose of rounded re/im for finals
    unsigned short* Tre = Al;                 // 128x64 u16 = 16 KB
    unsigned short* Tim = &Wl[0][0];          // spans Wl[0..1] = 16 KB
    #pragma unroll
    for (int mi = 0; mi < 4; ++mi) {
        #pragma unroll
        for (int ni = 0; ni < 2; ++ni) {
            int cl = wc * 32 + ni * 16 + (lane & 15);
            int rl = wr * 64 + mi * 16 + (lane >> 4) * 4;
            #pragma unroll
            for (int j = 0; j < 4; ++j) {
                unsigned short br = f2bf(acc[0][mi][ni][j]);
                unsigned short bi = f2bf(acc[1][mi][ni][j]);
                buri[(size_t)(m0 + rl + j) * 256 + n0 + cl] = ((unsigned int)bi << 16) | br;
                Tre[(rl + j) * 64 + cl] = br;
                Tim[(rl + j) * 64 + cl] = bi;
                float g = acc[2][mi][ni][j];
                sg[(size_t)(m0 + rl + j) * 256 + n0 + cl] = f2bf(1.0f / (1.0f + expf(-g)));
            }
        }
    }
    __syncthreads();
    {
        const int c = tid >> 6;          // local chunk 0..3
        const int col = tid & 63;
        const int dglob = n0 + col;
        const float lr_ = lam_re[dglob], li_ = lam_im[dglob];
        float hr = 0.0f, hi = 0.0f;
        #pragma unroll 8
        for (int k = 0; k < CLEN; ++k) {
            int row = c * 32 + k;
            float br = bf2f(Tre[row * 64 + col]);
            float bi = bf2f(Tim[row * 64 + col]);
            float nr = fmaf(lr_, hr, fmaf(-li_, hi, br));
            float ni = fmaf(lr_, hi, fmaf(li_, hr, bi));
            hr = nr; hi = ni;
        }
        const int b = m0 >> 12;
        const int cglob = ((m0 & 4095) >> 5) + c;
        float2 o; o.x = hr; o.y = hi;
        fin[((size_t)b * 256 + dglob) * 128 + cglob] = o;
    }
}

// ---------------- scan phase B: wave-parallel Kogge-Stone prefix over 128 chunks ---------------
__global__ __launch_bounds__(256) void scan_prefix_kernel(
    const float2* __restrict__ fin, float2* __restrict__ pre,
    const float* __restrict__ lamC_re, const float* __restrict__ lamC_im)
{
    const int lane = threadIdx.x & 63;
    const int w = blockIdx.x * 4 + (threadIdx.x >> 6);   // 0..2047 = b*256 + d
    const int d = w & 255;
    const float ar = lamC_re[d], ai = lamC_im[d];        // lambda^32
    const float4 f = *reinterpret_cast<const float4*>(fin + (size_t)w * 128 + lane * 2);
    const float f0r = f.x, f0i = f.y, f1r = f.z, f1i = f.w;
    float Tr = fmaf(ar, f0r, fmaf(-ai, f0i, f1r));
    float Ti = fmaf(ar, f0i, fmaf(ai, f0r, f1i));
    float Ar_ = ar * ar - ai * ai;
    float Ai_ = 2.0f * ar * ai;
    #pragma unroll
    for (int s = 1; s < 64; s <<= 1) {
        float ur = __shfl_up(Tr, s, 64);
        float ui = __shfl_up(Ti, s, 64);
        if (lane >= s) {
            Tr = fmaf(Ar_, ur, fmaf(-Ai_, ui, Tr));
            Ti = fmaf(Ar_, ui, fmaf(Ai_, ur, Ti));
        }
        float nr = Ar_ * Ar_ - Ai_ * Ai_;
        float ni = 2.0f * Ar_ * Ai_;
        Ar_ = nr; Ai_ = ni;
    }
    float Er = __shfl_up(Tr, 1, 64);
    float Ei = __shfl_up(Ti, 1, 64);
    if (lane == 0) { Er = 0.0f; Ei = 0.0f; }
    float P1r = fmaf(ar, Er, fmaf(-ai, Ei, f0r));
    float P1i = fmaf(ar, Ei, fmaf(ai, Er, f0i));
    float4 o; o.x = Er; o.y = Ei; o.z = P1r; o.w = P1i;
    *reinterpret_cast<float4*>(pre + (size_t)w * 128 + lane * 2) = o;
}

// ---------------- GEMM2: BM=64, BN=256, pipelined scan + GEMM + residual + next-layer LN -------
// Per ko (fully unrolled): issue W gload16 -> reg-chain scan on PRELOADED bu -> ds_write h ->
// prefetch next ko's bu -> counted-vmcnt barrier (prefetch stays in flight across MFMA) -> MFMA.
#define G2_LOAD_BU(dst, koff)                                              \
    {                                                                      \
        size_t gb = (size_t)(m0 + sc * 32) * 256 + (koff) + dl;            \
        _Pragma("unroll")                                                  \
        for (int k = 0; k < CLEN; ++k)                                     \
            dst[k] = buri[gb + (size_t)k * 256];                           \
    }

#define G2_CHAIN(src, kk)                                                  \
    {                                                                      \
        const int dg = kk * 64 + dl;                                       \
        const float lre = lam_re[dg], lim = lam_im[dg];                    \
        float hr = pre4[kk].x, hi = pre4[kk].y;                            \
        _Pragma("unroll")                                                  \
        for (int k = 0; k < CLEN; ++k) {                                   \
            unsigned int v = src[k];                                       \
            float br = bf2f((unsigned short)(v & 0xffffu));                \
            float bi = bf2f((unsigned short)(v >> 16));                    \
            float nr = fmaf(lre, hr, fmaf(-lim, hi, br));                  \
            float ni = fmaf(lre, hi, fmaf(lim, hr, bi));                   \
            hr = nr; hi = ni;                                              \
            int row = sc * 32 + k;                                         \
            int off = row * 64 + (((dl >> 3) ^ (row & 7)) * 8) + (dl & 7); \
            Ar[off] = f2bf(nr);                                            \
            Ai[off] = f2bf(ni);                                            \
        }                                                                  \
    }

__global__ __launch_bounds__(256) void gemm2_kernel(
    const unsigned int* __restrict__ buri,
    const unsigned short* __restrict__ wCre, const unsigned short* __restrict__ wCimn,
    const unsigned short* __restrict__ sg, const float2* __restrict__ pre,
    const float* __restrict__ lam_re, const float* __restrict__ lam_im,
    const float* __restrict__ scale, const float* __restrict__ bias,
    const float2* __restrict__ rowStats,
    const float* __restrict__ Dv, const float* __restrict__ uin, float* __restrict__ uout,
    const float* __restrict__ nscale, const float* __restrict__ nbias,
    unsigned short* __restrict__ zout, float2* __restrict__ statsOut, int writeLN)
{
    const int m0 = blockIdx.x * 64;

    __shared__ unsigned short Ar[64 * 64];     // 8 KB (h tile; reused as LN scratch)
    __shared__ unsigned short Ai[64 * 64];     // 8 KB
    __shared__ unsigned short Cr[256 * 64];    // 32 KB
    __shared__ unsigned short Ci[256 * 64];    // 32 KB

    const int tid = threadIdx.x;
    const int lane = tid & 63;
    const int wid = tid >> 6;
    const int lr = lane >> 3;
    const int lc = lane & 7;

    const int b = m0 >> 12;
    const int cbase = (m0 & 4095) >> 5;   // 2 chunks per block
    const bool isScan = (tid < 128);      // waves 0,1
    const int sc = tid >> 6;              // chunk 0/1 for scan threads
    const int dl = tid & 63;

    f32x4 acc[4][4] = {};

    // preload prefix seeds (all 4 ko) and the first bu tile
    float2 pre4[4];
    unsigned int vbuA[CLEN], vbuB[CLEN];
    if (isScan) {
        #pragma unroll
        for (int kk = 0; kk < 4; ++kk)
            pre4[kk] = pre[((size_t)b * 256 + kk * 64 + dl) * 128 + cbase + sc];
        G2_LOAD_BU(vbuA, 0)
    }

    #pragma unroll
    for (int kk = 0; kk < 4; ++kk) {
        const int ko = kk * 64;
        // ---- W stage issue first (oldest vmem => drained by counted wait) ----
        #pragma unroll
        for (int it = 0; it < 8; ++it) {
            int s = wid * 8 + it;
            int r = s * 8 + lr;
            int gc = lc ^ (r & 7);
            size_t off = (size_t)r * 256 + ko + gc * 8;
            gload16(wCre + off, &Cr[s * 512]);
            gload16(wCimn + off, &Ci[s * 512]);
        }
        asm volatile("" ::: "memory");   // pin W-issue before bu-prefetch

        if (isScan) {
            if ((kk & 1) == 0) {
                G2_CHAIN(vbuA, kk)
                if (kk < 3) G2_LOAD_BU(vbuB, ko + 64)
            } else {
                G2_CHAIN(vbuB, kk)
                if (kk < 3) G2_LOAD_BU(vbuA, ko + 64)
            }
        }

        // ---- counted-vmcnt barrier: W drained; bu prefetch (32 newest) stays in flight ----
        if (isScan) {
            if (kk < 3) asm volatile("s_waitcnt vmcnt(32) lgkmcnt(0)" ::: "memory");
            else        asm volatile("s_waitcnt vmcnt(0) lgkmcnt(0)" ::: "memory");
        } else {
            asm volatile("s_waitcnt vmcnt(0)" ::: "memory");
        }
        __builtin_amdgcn_s_barrier();
        __builtin_amdgcn_sched_barrier(0);

        #pragma unroll
        for (int k2 = 0; k2 < 64; k2 += 32) {
            int ac = (k2 >> 3) + (lane >> 4);
            bf16x8 are[4], aim[4];
            #pragma unroll
            for (int mi = 0; mi < 4; ++mi) {
                int arow = mi * 16 + (lane & 15);
                int idx = arow * 64 + ((ac ^ (arow & 7)) * 8);
                are[mi] = *reinterpret_cast<const bf16x8*>(&Ar[idx]);
                aim[mi] = *reinterpret_cast<const bf16x8*>(&Ai[idx]);
            }
            #pragma unroll
            for (int ni = 0; ni < 4; ++ni) {
                int brow = wid * 64 + ni * 16 + (lane & 15);
                int ib = brow * 64 + ((ac ^ (brow & 7)) * 8);
                bf16x8 bre = *reinterpret_cast<const bf16x8*>(&Cr[ib]);
                bf16x8 bim = *reinterpret_cast<const bf16x8*>(&Ci[ib]);
                #pragma unroll
                for (int mi = 0; mi < 4; ++mi) {
                    acc[mi][ni] = __builtin_amdgcn_mfma_f32_16x16x32_bf16(are[mi], bre, acc[mi][ni], 0, 0, 0);
                    acc[mi][ni] = __builtin_amdgcn_mfma_f32_16x16x32_bf16(aim[mi], bim, acc[mi][ni], 0, 0, 0);
                }
            }
        }
        asm volatile("s_waitcnt lgkmcnt(0)" ::: "memory");
        __builtin_amdgcn_s_barrier();    // protect Ar/Ai/Cr/Ci before next stage
    }

    // ---- epilogue: uout + rs/rs2; z recomputed from re-read uout (no uvals -> no spill) ----
    float rs[4][4], rs2[4][4];
    #pragma unroll
    for (int mi = 0; mi < 4; ++mi)
        #pragma unroll
        for (int j = 0; j < 4; ++j) { rs[mi][j] = 0.0f; rs2[mi][j] = 0.0f; }

    #pragma unroll
    for (int mi = 0; mi < 4; ++mi) {
        #pragma unroll
        for (int ni = 0; ni < 4; ++ni) {
            int col = wid * 64 + ni * 16 + (lane & 15);
            int mrow = m0 + mi * 16 + (lane >> 4) * 4;
            float dv = Dv[col];
            float scc = scale[col], bcc = bias[col];
            #pragma unroll
            for (int j = 0; j < 4; ++j) {
                size_t idx = (size_t)(mrow + j) * 256 + col;
                float2 st = rowStats[mrow + j];
                float uv = uin[idx];
                float zz = (uv - st.x) * st.y * scc + bcc;
                float s = bf2f(sg[idx]);
                float o = uv + (acc[mi][ni][j] + dv * zz) * s;
                uout[idx] = o;
                rs[mi][j] += o;
                rs2[mi][j] += o * o;
            }
        }
    }

    if (writeLN) {
        #pragma unroll
        for (int mi = 0; mi < 4; ++mi)
            #pragma unroll
            for (int j = 0; j < 4; ++j)
                #pragma unroll
                for (int off = 1; off < 16; off <<= 1) {
                    rs[mi][j]  += __shfl_xor(rs[mi][j], off);
                    rs2[mi][j] += __shfl_xor(rs2[mi][j], off);
                }
        float* sS   = (float*)Ar;        // aliases dead Ar (16 KB total available)
        float* sS2  = sS + 256;
        float* sMu  = sS2 + 256;
        float* sInv = sMu + 64;
        __syncthreads();
        if ((lane & 15) == 0) {
            int hi = lane >> 4;
            #pragma unroll
            for (int mi = 0; mi < 4; ++mi)
                #pragma unroll
                for (int j = 0; j < 4; ++j) {
                    int row = mi * 16 + hi * 4 + j;
                    sS[wid * 64 + row]  = rs[mi][j];
                    sS2[wid * 64 + row] = rs2[mi][j];
                }
        }
        __syncthreads();
        if (tid < 64) {
            float s  = sS[tid] + sS[64 + tid] + sS[128 + tid] + sS[192 + tid];
            float s2 = sS2[tid] + sS2[64 + tid] + sS2[128 + tid] + sS2[192 + tid];
            float mu  = s * (1.0f / 256.0f);
            float var = s2 * (1.0f / 256.0f) - mu * mu;
            float inv = rsqrtf(var + 1e-5f);
            sMu[tid] = mu; sInv[tid] = inv;
            float2 st; st.x = mu; st.y = inv;
            statsOut[m0 + tid] = st;
        }
        __syncthreads();
        #pragma unroll
        for (int mi = 0; mi < 4; ++mi) {
            #pragma unroll
            for (int ni = 0; ni < 4; ++ni) {
                int col = wid * 64 + ni * 16 + (lane & 15);
                float nsc = nscale[col], nbi = nbias[col];
                #pragma unroll
                for (int j = 0; j < 4; ++j) {
                    int row = mi * 16 + (lane >> 4) * 4 + j;
                    size_t idx = (size_t)(m0 + row) * 256 + col;
                    float o = uout[idx];      // re-read own write, L2-hot
                    float zz = (o - sMu[row]) * sInv[row] * nsc + nbi;
                    zout[idx] = f2bf(zz);
                }
            }
        }
    }
}

extern "C" void kernel_launch(void* const* d_in, const int* in_sizes, int n_in,
                              void* d_out, int out_size, void* d_ws, size_t ws_size,
                              hipStream_t stream) {
    const float* x         = (const float*)d_in[0];
    const float* nu_log    = (const float*)d_in[1];
    const float* theta_log = (const float*)d_in[2];
    const float* gamma_log = (const float*)d_in[3];
    const float* B_re      = (const float*)d_in[4];
    const float* B_im      = (const float*)d_in[5];
    const float* C_re      = (const float*)d_in[6];
    const float* C_im      = (const float*)d_in[7];
    const float* D_vec     = (const float*)d_in[8];
    const float* Wg        = (const float*)d_in[9];
    const float* ln_scale  = (const float*)d_in[10];
    const float* ln_bias   = (const float*)d_in[11];
    float* out = (float*)d_out;

    const size_t MSZ = (size_t)MROWS * DDIM;
    const size_t WSZ = (size_t)NLAYER * DDIM * DDIM;
    const size_t FSZ = (size_t)NBATCH * DDIM * NCHUNK;   // 262144 float2

    unsigned short* b16 = (unsigned short*)d_ws;
    unsigned short* z     = b16;
    unsigned short* sg    = b16 + MSZ;
    unsigned int*   buri  = (unsigned int*)(b16 + 2 * MSZ);   // spans 2*MSZ u16
    unsigned short* wBre  = b16 + 4 * MSZ;
    unsigned short* wBim  = wBre + WSZ;
    unsigned short* wWg   = wBim + WSZ;
    unsigned short* wCre  = wWg + WSZ;
    unsigned short* wCimn = wCre + WSZ;
    float* lam_re  = (float*)(wCimn + WSZ);
    float* lam_im  = lam_re + NLAYER * DDIM;
    float* lamC_re = lam_im + NLAYER * DDIM;
    float* lamC_im = lamC_re + NLAYER * DDIM;
    float2* fin = (float2*)(lamC_im + NLAYER * DDIM);
    float2* pre = fin + FSZ;
    float2* statsA = pre + FSZ;          // ping-pong row stats
    float2* statsB = statsA + MROWS;

    prepack_kernel<<<1024, 256, 0, stream>>>(nu_log, theta_log, gamma_log,
                                             B_re, B_im, C_re, C_im, Wg,
                                             wBre, wBim, wWg, wCre, wCimn,
                                             lam_re, lam_im, lamC_re, lamC_im);

    // layer 0 LN on x
    ln_kernel<<<MROWS / 4, 256, 0, stream>>>(x, z, ln_scale, ln_bias, statsA);

    for (int l = 0; l < NLAYER; ++l) {
        const float* uin = (l == 0) ? x : out;
        const float* lre = lam_re + l * DDIM;
        const float* lim = lam_im + l * DDIM;
        float2* statsIn  = (l & 1) ? statsB : statsA;
        float2* statsOut = (l & 1) ? statsA : statsB;
        int nl = (l < NLAYER - 1) ? (l + 1) : l;   // next-layer params (unused when writeLN=0)
        gemm1_kernel<<<dim3(MROWS / 128, 4), 256, 0, stream>>>(
            z, wBre + l * DDIM * DDIM, wBim + l * DDIM * DDIM, wWg + l * DDIM * DDIM,
            buri, sg, lre, lim, fin);
        scan_prefix_kernel<<<512, 256, 0, stream>>>(fin, pre,
                                                    lamC_re + l * DDIM, lamC_im + l * DDIM);
        gemm2_kernel<<<MROWS / 64, 256, 0, stream>>>(
            buri, wCre + l * DDIM * DDIM, wCimn + l * DDIM * DDIM,
            sg, pre, lre, lim,
            ln_scale + l * DDIM, ln_bias + l * DDIM, statsIn,
            D_vec + l * DDIM, uin, out,
            ln_scale + nl * DDIM, ln_bias + nl * DDIM,
            z, statsOut, (l < NLAYER - 1) ? 1 : 0);
    }
}

// Round 12
// 273.677 us; speedup vs baseline: 1.2820x; 1.2820x over previous
//
#include <hip/hip_runtime.h>
#include <hip/hip_bf16.h>

#define NLAYER 4
#define DDIM 256
#define TSEQ 4096
#define NBATCH 8
#define MROWS (NBATCH * TSEQ)   // 32768
#define CLEN 32                 // chunk length for parallel scan
#define NCHUNK (TSEQ / CLEN)    // 128

typedef float f32x4 __attribute__((ext_vector_type(4)));
typedef short bf16x8 __attribute__((ext_vector_type(8)));

__device__ __forceinline__ float bf2f(unsigned short u) {
    union { unsigned int i; float f; } v; v.i = ((unsigned int)u) << 16; return v.f;
}
__device__ __forceinline__ unsigned short f2bf(float f) {
    union { float f; unsigned int i; } v; v.f = f;
    unsigned int r = v.i + 0x7fffu + ((v.i >> 16) & 1u);
    return (unsigned short)(r >> 16);
}

// async global->LDS, 16B per lane; lds base must be wave-uniform (HW adds lane*16)
__device__ __forceinline__ void gload16(const unsigned short* g, unsigned short* l) {
    __builtin_amdgcn_global_load_lds(
        (const __attribute__((address_space(1))) unsigned int*)g,
        (__attribute__((address_space(3))) unsigned int*)l, 16, 0, 0);
}

// ---------------- prepack: weights -> bf16 (gamma folded into B, -C_im), lambda, lambda^CLEN ----
__global__ __launch_bounds__(256) void prepack_kernel(
    const float* __restrict__ nu_log, const float* __restrict__ theta_log,
    const float* __restrict__ gamma_log,
    const float* __restrict__ B_re, const float* __restrict__ B_im,
    const float* __restrict__ C_re, const float* __restrict__ C_im,
    const float* __restrict__ Wg,
    unsigned short* __restrict__ wBre, unsigned short* __restrict__ wBim,
    unsigned short* __restrict__ wWg, unsigned short* __restrict__ wCre,
    unsigned short* __restrict__ wCimn,
    float* __restrict__ lam_re, float* __restrict__ lam_im,
    float* __restrict__ lamC_re, float* __restrict__ lamC_im)
{
    int idx = blockIdx.x * 256 + threadIdx.x;
    const int total = NLAYER * DDIM * DDIM;
    if (idx < total) {
        int l = idx >> 16;
        int e = (idx >> 8) & 255;
        float gam = expf(gamma_log[l * DDIM + e]);
        wBre[idx]  = f2bf(B_re[idx] * gam);
        wBim[idx]  = f2bf(B_im[idx] * gam);
        wWg[idx]   = f2bf(Wg[idx]);
        wCre[idx]  = f2bf(C_re[idx]);
        wCimn[idx] = f2bf(-C_im[idx]);
    }
    if (idx < NLAYER * DDIM) {
        float mag = expf(-expf(nu_log[idx]));
        float th  = expf(theta_log[idx]);
        float ar = mag * cosf(th);
        float ai = mag * sinf(th);
        lam_re[idx] = ar;
        lam_im[idx] = ai;
        #pragma unroll
        for (int s = 0; s < 5; ++s) {   // lambda^32
            float nr = ar * ar - ai * ai;
            float ni = 2.0f * ar * ai;
            ar = nr; ai = ni;
        }
        lamC_re[idx] = ar;
        lamC_im[idx] = ai;
    }
}

// ---------------- LayerNorm (layer 0 only): one wave per row, 4 rows/block ---------------------
__global__ __launch_bounds__(256) void ln_kernel(
    const float* __restrict__ u, unsigned short* __restrict__ z,
    const float* __restrict__ scale, const float* __restrict__ bias,
    float2* __restrict__ rowStats)
{
    int wid = threadIdx.x >> 6;
    int lane = threadIdx.x & 63;
    int row = blockIdx.x * 4 + wid;
    const float4 v = *reinterpret_cast<const float4*>(u + (size_t)row * DDIM + lane * 4);
    float s  = v.x + v.y + v.z + v.w;
    float s2 = v.x * v.x + v.y * v.y + v.z * v.z + v.w * v.w;
    #pragma unroll
    for (int off = 32; off > 0; off >>= 1) {
        s  += __shfl_xor(s, off);
        s2 += __shfl_xor(s2, off);
    }
    float mu  = s * (1.0f / DDIM);
    float var = s2 * (1.0f / DDIM) - mu * mu;
    float inv = rsqrtf(var + 1e-5f);
    if (lane == 0) { float2 st; st.x = mu; st.y = inv; rowStats[row] = st; }
    float zv[4] = { v.x, v.y, v.z, v.w };
    ushort4 o;
    unsigned short* op = (unsigned short*)&o;
    #pragma unroll
    for (int j = 0; j < 4; ++j) {
        int d = lane * 4 + j;
        op[j] = f2bf((zv[j] - mu) * inv * scale[d] + bias[d]);
    }
    *reinterpret_cast<ushort4*>(z + (size_t)row * DDIM + lane * 4) = o;
}

// ---------------- GEMM1 (fused 3-matrix) + chunk-finals epilogue --------------------------------
// grid (256, 4): m0 = bx*128, n0 = by*64. Writes bu INTERLEAVED (im<<16|re) into buri.
__global__ __launch_bounds__(256) void gemm1_kernel(
    const unsigned short* __restrict__ z,
    const unsigned short* __restrict__ wBre, const unsigned short* __restrict__ wBim,
    const unsigned short* __restrict__ wWg,
    unsigned int* __restrict__ buri, unsigned short* __restrict__ sg,
    const float* __restrict__ lam_re, const float* __restrict__ lam_im,
    float2* __restrict__ fin)
{
    const int m0 = blockIdx.x * 128;
    const int n0 = blockIdx.y * 64;

    __shared__ unsigned short Al[128 * 64];      // 16 KB
    __shared__ unsigned short Wl[3][64 * 64];    // 24 KB

    const int tid = threadIdx.x;
    const int lane = tid & 63;
    const int wid = tid >> 6;
    const int wr = wid >> 1, wc = wid & 1;
    const int lr = lane >> 3;      // row within 8-row segment
    const int lc = lane & 7;       // 16B chunk within row

    f32x4 acc[3][4][2] = {};

    for (int ko = 0; ko < 256; ko += 64) {
        #pragma unroll
        for (int it = 0; it < 4; ++it) {
            int s = wid * 4 + it;
            int r = s * 8 + lr;
            int gc = lc ^ (r & 7);
            gload16(z + (size_t)(m0 + r) * 256 + ko + gc * 8, &Al[s * 512]);
        }
        #pragma unroll
        for (int it = 0; it < 2; ++it) {
            int s = wid * 2 + it;
            int r = s * 8 + lr;
            int gc = lc ^ (r & 7);
            size_t off = (size_t)(n0 + r) * 256 + ko + gc * 8;
            gload16(wBre + off, &Wl[0][s * 512]);
            gload16(wBim + off, &Wl[1][s * 512]);
            gload16(wWg  + off, &Wl[2][s * 512]);
        }
        __syncthreads();

        #pragma unroll
        for (int k2 = 0; k2 < 64; k2 += 32) {
            int ac = (k2 >> 3) + (lane >> 4);
            bf16x8 a[4];
            #pragma unroll
            for (int mi = 0; mi < 4; ++mi) {
                int ar = wr * 64 + mi * 16 + (lane & 15);
                a[mi] = *reinterpret_cast<const bf16x8*>(&Al[ar * 64 + ((ac ^ (ar & 7)) * 8)]);
            }
            int br0 = wc * 32 + (lane & 15);
            int br1 = br0 + 16;
            #pragma unroll
            for (int mat = 0; mat < 3; ++mat) {
                bf16x8 b0 = *reinterpret_cast<const bf16x8*>(&Wl[mat][br0 * 64 + ((ac ^ (br0 & 7)) * 8)]);
                bf16x8 b1 = *reinterpret_cast<const bf16x8*>(&Wl[mat][br1 * 64 + ((ac ^ (br1 & 7)) * 8)]);
                #pragma unroll
                for (int mi = 0; mi < 4; ++mi) {
                    acc[mat][mi][0] = __builtin_amdgcn_mfma_f32_16x16x32_bf16(a[mi], b0, acc[mat][mi][0], 0, 0, 0);
                    acc[mat][mi][1] = __builtin_amdgcn_mfma_f32_16x16x32_bf16(a[mi], b1, acc[mat][mi][1], 0, 0, 0);
                }
            }
        }
        __syncthreads();
    }

    // global writes (buri packed, sg) + LDS transpose of rounded re/im for finals
    unsigned short* Tre = Al;                 // 128x64 u16 = 16 KB
    unsigned short* Tim = &Wl[0][0];          // spans Wl[0..1] = 16 KB
    #pragma unroll
    for (int mi = 0; mi < 4; ++mi) {
        #pragma unroll
        for (int ni = 0; ni < 2; ++ni) {
            int cl = wc * 32 + ni * 16 + (lane & 15);
            int rl = wr * 64 + mi * 16 + (lane >> 4) * 4;
            #pragma unroll
            for (int j = 0; j < 4; ++j) {
                unsigned short br = f2bf(acc[0][mi][ni][j]);
                unsigned short bi = f2bf(acc[1][mi][ni][j]);
                buri[(size_t)(m0 + rl + j) * 256 + n0 + cl] = ((unsigned int)bi << 16) | br;
                Tre[(rl + j) * 64 + cl] = br;
                Tim[(rl + j) * 64 + cl] = bi;
                float g = acc[2][mi][ni][j];
                sg[(size_t)(m0 + rl + j) * 256 + n0 + cl] = f2bf(1.0f / (1.0f + expf(-g)));
            }
        }
    }
    __syncthreads();
    {
        const int c = tid >> 6;          // local chunk 0..3
        const int col = tid & 63;
        const int dglob = n0 + col;
        const float lr_ = lam_re[dglob], li_ = lam_im[dglob];
        float hr = 0.0f, hi = 0.0f;
        #pragma unroll 8
        for (int k = 0; k < CLEN; ++k) {
            int row = c * 32 + k;
            float br = bf2f(Tre[row * 64 + col]);
            float bi = bf2f(Tim[row * 64 + col]);
            float nr = fmaf(lr_, hr, fmaf(-li_, hi, br));
            float ni = fmaf(lr_, hi, fmaf(li_, hr, bi));
            hr = nr; hi = ni;
        }
        const int b = m0 >> 12;
        const int cglob = ((m0 & 4095) >> 5) + c;
        float2 o; o.x = hr; o.y = hi;
        fin[((size_t)b * 256 + dglob) * 128 + cglob] = o;
    }
}

// ---------------- scan phase B: wave-parallel Kogge-Stone prefix over 128 chunks ---------------
__global__ __launch_bounds__(256) void scan_prefix_kernel(
    const float2* __restrict__ fin, float2* __restrict__ pre,
    const float* __restrict__ lamC_re, const float* __restrict__ lamC_im)
{
    const int lane = threadIdx.x & 63;
    const int w = blockIdx.x * 4 + (threadIdx.x >> 6);   // 0..2047 = b*256 + d
    const int d = w & 255;
    const float ar = lamC_re[d], ai = lamC_im[d];        // lambda^32
    const float4 f = *reinterpret_cast<const float4*>(fin + (size_t)w * 128 + lane * 2);
    const float f0r = f.x, f0i = f.y, f1r = f.z, f1i = f.w;
    float Tr = fmaf(ar, f0r, fmaf(-ai, f0i, f1r));
    float Ti = fmaf(ar, f0i, fmaf(ai, f0r, f1i));
    float Ar_ = ar * ar - ai * ai;
    float Ai_ = 2.0f * ar * ai;
    #pragma unroll
    for (int s = 1; s < 64; s <<= 1) {
        float ur = __shfl_up(Tr, s, 64);
        float ui = __shfl_up(Ti, s, 64);
        if (lane >= s) {
            Tr = fmaf(Ar_, ur, fmaf(-Ai_, ui, Tr));
            Ti = fmaf(Ar_, ui, fmaf(Ai_, ur, Ti));
        }
        float nr = Ar_ * Ar_ - Ai_ * Ai_;
        float ni = 2.0f * Ar_ * Ai_;
        Ar_ = nr; Ai_ = ni;
    }
    float Er = __shfl_up(Tr, 1, 64);
    float Ei = __shfl_up(Ti, 1, 64);
    if (lane == 0) { Er = 0.0f; Ei = 0.0f; }
    float P1r = fmaf(ar, Er, fmaf(-ai, Ei, f0r));
    float P1i = fmaf(ar, Ei, fmaf(ai, Er, f0i));
    float4 o; o.x = Er; o.y = Ei; o.z = P1r; o.w = P1i;
    *reinterpret_cast<float4*>(pre + (size_t)w * 128 + lane * 2) = o;
}

// ---------------- GEMM2: BM=64, BN=256, fused scan-apply + GEMM + residual + next-layer LN -----
// Round-9 sync structure (plain __syncthreads; compiler schedules waits). Per ko:
// issue W gload16 -> scan threads load packed bu from GLOBAL into regs, chain, ds_write h ->
// barrier -> MFMA -> barrier.
__global__ __launch_bounds__(256) void gemm2_kernel(
    const unsigned int* __restrict__ buri,
    const unsigned short* __restrict__ wCre, const unsigned short* __restrict__ wCimn,
    const unsigned short* __restrict__ sg, const float2* __restrict__ pre,
    const float* __restrict__ lam_re, const float* __restrict__ lam_im,
    const float* __restrict__ scale, const float* __restrict__ bias,
    const float2* __restrict__ rowStats,
    const float* __restrict__ Dv, const float* __restrict__ uin, float* __restrict__ uout,
    const float* __restrict__ nscale, const float* __restrict__ nbias,
    unsigned short* __restrict__ zout, float2* __restrict__ statsOut, int writeLN)
{
    const int m0 = blockIdx.x * 64;

    __shared__ unsigned short Ar[64 * 64];     // 8 KB (h tile; reused as LN scratch)
    __shared__ unsigned short Ai[64 * 64];     // 8 KB
    __shared__ unsigned short Cr[256 * 64];    // 32 KB
    __shared__ unsigned short Ci[256 * 64];    // 32 KB

    const int tid = threadIdx.x;
    const int lane = tid & 63;
    const int wid = tid >> 6;
    const int lr = lane >> 3;
    const int lc = lane & 7;

    const int b = m0 >> 12;
    const int cbase = (m0 & 4095) >> 5;   // 2 chunks per block

    f32x4 acc[4][4] = {};

    for (int ko = 0; ko < 256; ko += 64) {
        // ---- issue W staging first; its latency hides under the scan below ----
        #pragma unroll
        for (int it = 0; it < 8; ++it) {
            int s = wid * 8 + it;
            int r = s * 8 + lr;
            int gc = lc ^ (r & 7);
            size_t off = (size_t)r * 256 + ko + gc * 8;
            gload16(wCre + off, &Cr[s * 512]);
            gload16(wCimn + off, &Ci[s * 512]);
        }

        // ---- scan: chain in REGISTERS (packed global bu -> regs -> ds_write h) ----
        if (tid < 128) {
            const int c = tid >> 6;       // chunk 0..1 (wave-uniform)
            const int dl = tid & 63;      // local d (lane) -> coalesced 256B per k
            const int dg = ko + dl;
            const float lre = lam_re[dg], lim = lam_im[dg];
            float2 p = pre[((size_t)b * 256 + dg) * 128 + cbase + c];
            unsigned int vri[CLEN];
            size_t gbase = (size_t)(m0 + c * 32) * 256 + dg;
            #pragma unroll
            for (int k = 0; k < CLEN; ++k)        // independent loads -> pipelined
                vri[k] = buri[gbase + (size_t)k * 256];
            float hr = p.x, hi = p.y;
            #pragma unroll
            for (int k = 0; k < CLEN; ++k) {      // register chain, no LDS aliasing
                unsigned int v = vri[k];
                float br = bf2f((unsigned short)(v & 0xffffu));
                float bi = bf2f((unsigned short)(v >> 16));
                float nr = fmaf(lre, hr, fmaf(-lim, hi, br));
                float ni = fmaf(lre, hi, fmaf(lim, hr, bi));
                hr = nr; hi = ni;
                int row = c * 32 + k;
                int off = row * 64 + (((dl >> 3) ^ (row & 7)) * 8) + (dl & 7);
                Ar[off] = f2bf(nr);
                Ai[off] = f2bf(ni);
            }
        }
        __syncthreads();   // drains W gload16 (vmcnt) + scan ds_writes (lgkm)

        #pragma unroll
        for (int k2 = 0; k2 < 64; k2 += 32) {
            int ac = (k2 >> 3) + (lane >> 4);
            bf16x8 are[4], aim[4];
            #pragma unroll
            for (int mi = 0; mi < 4; ++mi) {
                int arow = mi * 16 + (lane & 15);
                int idx = arow * 64 + ((ac ^ (arow & 7)) * 8);
                are[mi] = *reinterpret_cast<const bf16x8*>(&Ar[idx]);
                aim[mi] = *reinterpret_cast<const bf16x8*>(&Ai[idx]);
            }
            #pragma unroll
            for (int ni = 0; ni < 4; ++ni) {
                int brow = wid * 64 + ni * 16 + (lane & 15);
                int ib = brow * 64 + ((ac ^ (brow & 7)) * 8);
                bf16x8 bre = *reinterpret_cast<const bf16x8*>(&Cr[ib]);
                bf16x8 bim = *reinterpret_cast<const bf16x8*>(&Ci[ib]);
                #pragma unroll
                for (int mi = 0; mi < 4; ++mi) {
                    acc[mi][ni] = __builtin_amdgcn_mfma_f32_16x16x32_bf16(are[mi], bre, acc[mi][ni], 0, 0, 0);
                    acc[mi][ni] = __builtin_amdgcn_mfma_f32_16x16x32_bf16(aim[mi], bim, acc[mi][ni], 0, 0, 0);
                }
            }
        }
        __syncthreads();
    }

    // ---- epilogue: uout + (optional) fused next-layer LN ----
    float uvals[4][4][4];
    float rs[4][4], rs2[4][4];
    #pragma unroll
    for (int mi = 0; mi < 4; ++mi)
        #pragma unroll
        for (int j = 0; j < 4; ++j) { rs[mi][j] = 0.0f; rs2[mi][j] = 0.0f; }

    #pragma unroll
    for (int mi = 0; mi < 4; ++mi) {
        #pragma unroll
        for (int ni = 0; ni < 4; ++ni) {
            int col = wid * 64 + ni * 16 + (lane & 15);
            int mrow = m0 + mi * 16 + (lane >> 4) * 4;
            float dv = Dv[col];
            float scc = scale[col], bcc = bias[col];
            #pragma unroll
            for (int j = 0; j < 4; ++j) {
                size_t idx = (size_t)(mrow + j) * 256 + col;
                float2 st = rowStats[mrow + j];
                float uv = uin[idx];
                float zz = (uv - st.x) * st.y * scc + bcc;
                float s = bf2f(sg[idx]);
                float o = uv + (acc[mi][ni][j] + dv * zz) * s;
                uout[idx] = o;
                uvals[mi][ni][j] = o;
                rs[mi][j] += o;
                rs2[mi][j] += o * o;
            }
        }
    }

    if (writeLN) {
        // reduce over the 16 low lanes (each wave covers 64 cols; 4 waves = 256 cols)
        #pragma unroll
        for (int mi = 0; mi < 4; ++mi)
            #pragma unroll
            for (int j = 0; j < 4; ++j)
                #pragma unroll
                for (int off = 1; off < 16; off <<= 1) {
                    rs[mi][j]  += __shfl_xor(rs[mi][j], off);
                    rs2[mi][j] += __shfl_xor(rs2[mi][j], off);
                }
        float* sS   = (float*)Ar;        // [4][64] per-wave partial sums (aliases dead Ar)
        float* sS2  = sS + 256;          // [4][64]
        float* sMu  = sS2 + 256;         // [64]
        float* sInv = sMu + 64;          // [64]
        __syncthreads();                 // all ds_reads of Ar done (post-K-loop barrier passed)
        if ((lane & 15) == 0) {
            int hi = lane >> 4;
            #pragma unroll
            for (int mi = 0; mi < 4; ++mi)
                #pragma unroll
                for (int j = 0; j < 4; ++j) {
                    int row = mi * 16 + hi * 4 + j;
                    sS[wid * 64 + row]  = rs[mi][j];
                    sS2[wid * 64 + row] = rs2[mi][j];
                }
        }
        __syncthreads();
        if (tid < 64) {
            float s  = sS[tid] + sS[64 + tid] + sS[128 + tid] + sS[192 + tid];
            float s2 = sS2[tid] + sS2[64 + tid] + sS2[128 + tid] + sS2[192 + tid];
            float mu  = s * (1.0f / 256.0f);
            float var = s2 * (1.0f / 256.0f) - mu * mu;
            float inv = rsqrtf(var + 1e-5f);
            sMu[tid] = mu; sInv[tid] = inv;
            float2 st; st.x = mu; st.y = inv;
            statsOut[m0 + tid] = st;
        }
        __syncthreads();
        #pragma unroll
        for (int mi = 0; mi < 4; ++mi) {
            #pragma unroll
            for (int ni = 0; ni < 4; ++ni) {
                int col = wid * 64 + ni * 16 + (lane & 15);
                float nsc = nscale[col], nbi = nbias[col];
                #pragma unroll
                for (int j = 0; j < 4; ++j) {
                    int row = mi * 16 + (lane >> 4) * 4 + j;
                    float zz = (uvals[mi][ni][j] - sMu[row]) * sInv[row] * nsc + nbi;
                    zout[(size_t)(m0 + row) * 256 + col] = f2bf(zz);
                }
            }
        }
    }
}

extern "C" void kernel_launch(void* const* d_in, const int* in_sizes, int n_in,
                              void* d_out, int out_size, void* d_ws, size_t ws_size,
                              hipStream_t stream) {
    const float* x         = (const float*)d_in[0];
    const float* nu_log    = (const float*)d_in[1];
    const float* theta_log = (const float*)d_in[2];
    const float* gamma_log = (const float*)d_in[3];
    const float* B_re      = (const float*)d_in[4];
    const float* B_im      = (const float*)d_in[5];
    const float* C_re      = (const float*)d_in[6];
    const float* C_im      = (const float*)d_in[7];
    const float* D_vec     = (const float*)d_in[8];
    const float* Wg        = (const float*)d_in[9];
    const float* ln_scale  = (const float*)d_in[10];
    const float* ln_bias   = (const float*)d_in[11];
    float* out = (float*)d_out;

    const size_t MSZ = (size_t)MROWS * DDIM;
    const size_t WSZ = (size_t)NLAYER * DDIM * DDIM;
    const size_t FSZ = (size_t)NBATCH * DDIM * NCHUNK;   // 262144 float2

    unsigned short* b16 = (unsigned short*)d_ws;
    unsigned short* z     = b16;
    unsigned short* sg    = b16 + MSZ;
    unsigned int*   buri  = (unsigned int*)(b16 + 2 * MSZ);   // spans 2*MSZ u16
    unsigned short* wBre  = b16 + 4 * MSZ;
    unsigned short* wBim  = wBre + WSZ;
    unsigned short* wWg   = wBim + WSZ;
    unsigned short* wCre  = wWg + WSZ;
    unsigned short* wCimn = wCre + WSZ;
    float* lam_re  = (float*)(wCimn + WSZ);
    float* lam_im  = lam_re + NLAYER * DDIM;
    float* lamC_re = lam_im + NLAYER * DDIM;
    float* lamC_im = lamC_re + NLAYER * DDIM;
    float2* fin = (float2*)(lamC_im + NLAYER * DDIM);
    float2* pre = fin + FSZ;
    float2* statsA = pre + FSZ;          // ping-pong row stats
    float2* statsB = statsA + MROWS;

    prepack_kernel<<<1024, 256, 0, stream>>>(nu_log, theta_log, gamma_log,
                                             B_re, B_im, C_re, C_im, Wg,
                                             wBre, wBim, wWg, wCre, wCimn,
                                             lam_re, lam_im, lamC_re, lamC_im);

    // layer 0 LN on x
    ln_kernel<<<MROWS / 4, 256, 0, stream>>>(x, z, ln_scale, ln_bias, statsA);

    for (int l = 0; l < NLAYER; ++l) {
        const float* uin = (l == 0) ? x : out;
        const float* lre = lam_re + l * DDIM;
        const float* lim = lam_im + l * DDIM;
        float2* statsIn  = (l & 1) ? statsB : statsA;
        float2* statsOut = (l & 1) ? statsA : statsB;
        int nl = (l < NLAYER - 1) ? (l + 1) : l;   // next-layer params (unused when writeLN=0)
        gemm1_kernel<<<dim3(MROWS / 128, 4), 256, 0, stream>>>(
            z, wBre + l * DDIM * DDIM, wBim + l * DDIM * DDIM, wWg + l * DDIM * DDIM,
            buri, sg, lre, lim, fin);
        scan_prefix_kernel<<<512, 256, 0, stream>>>(fin, pre,
                                                    lamC_re + l * DDIM, lamC_im + l * DDIM);
        gemm2_kernel<<<MROWS / 64, 256, 0, stream>>>(
            buri, wCre + l * DDIM * DDIM, wCimn + l * DDIM * DDIM,
            sg, pre, lre, lim,
            ln_scale + l * DDIM, ln_bias + l * DDIM, statsIn,
            D_vec + l * DDIM, uin, out,
            ln_scale + nl * DDIM, ln_bias + nl * DDIM,
            z, statsOut, (l < NLAYER - 1) ? 1 : 0);
    }
}